// Round 1
// baseline (33.741 us; speedup 1.0000x reference)
//
#include <hip/hip_runtime.h>
#include <math.h>

// Problem constants (from reference)
#define B_SZ 256
#define U_SZ 4096
#define V_SZ 80
#define H_SZ 1024
#define K_SZ 10

// d_out layout (floats, concatenated in return order):
//   [0, B*V)                       w            (256*80   = 20480)
//   [B*V, B*V + B*K)               new_kappa    (256*10   = 2560)
//   [B*V + B*K, ... + B*(U+1))     phi_term     (256*4097 = 1048832)
#define OUT_W_OFF      0
#define OUT_NK_OFF     (B_SZ * V_SZ)
#define OUT_PT_OFF     (B_SZ * V_SZ + B_SZ * K_SZ)

// d_ws layout (floats):
//   [0, B*K)           alpha
//   [B*K, 2*B*K)       beta
//   [2*B*K, 3*B*K)     new_kappa
//   [3*B*K, 3*B*K+B)   umax (int, one per batch)
//   [3*B*K+B, +B*U)    masked phi
#define WS_ALPHA_OFF   0
#define WS_BETA_OFF    (B_SZ * K_SZ)
#define WS_NK_OFF      (2 * B_SZ * K_SZ)
#define WS_UMAX_OFF    (3 * B_SZ * K_SZ)
#define WS_PHI_OFF     (3 * B_SZ * K_SZ + B_SZ)

// Kernel 1: per-batch lin = x @ W.T + b, then alpha/beta/new_kappa; init umax.
__global__ __launch_bounds__(256) void k1_lin(const float* __restrict__ x,
                                              const float* __restrict__ kappa,
                                              const float* __restrict__ W,
                                              const float* __restrict__ bias,
                                              float* __restrict__ ws,
                                              float* __restrict__ out) {
    __shared__ float xs[H_SZ];
    __shared__ float lin_s[32];
    const int b = blockIdx.x;
    const int tid = threadIdx.x;
    const float* xb = x + (size_t)b * H_SZ;
    for (int h = tid; h < H_SZ; h += 256) xs[h] = xb[h];
    __syncthreads();

    const int wave = tid >> 6;
    const int lane = tid & 63;
    // 4 waves cover 30 outputs round-robin
    for (int k = wave; k < 3 * K_SZ; k += 4) {
        const float* Wk = W + (size_t)k * H_SZ;
        float p = 0.f;
        #pragma unroll
        for (int h = lane; h < H_SZ; h += 64) p += xs[h] * Wk[h];
        #pragma unroll
        for (int off = 32; off > 0; off >>= 1) p += __shfl_down(p, off);
        if (lane == 0) lin_s[k] = p;
    }
    __syncthreads();

    if (tid < K_SZ) {
        const int k = tid;
        float a  = expf(lin_s[k]            + bias[k]);
        float bt = expf(lin_s[K_SZ + k]     + bias[K_SZ + k]);
        float nk = kappa[(size_t)b * K_SZ + k] +
                   expf(lin_s[2 * K_SZ + k] + bias[2 * K_SZ + k] - 3.9f);
        ws[WS_ALPHA_OFF + b * K_SZ + k] = a;
        ws[WS_BETA_OFF  + b * K_SZ + k] = bt;
        ws[WS_NK_OFF    + b * K_SZ + k] = nk;
        out[OUT_NK_OFF  + b * K_SZ + k] = nk;
    }
    if (tid == 0) {
        int* umax = (int*)(ws + WS_UMAX_OFF);
        umax[b] = -1;  // re-init every call (deterministic)
    }
}

// Kernel 2: phi_termination for u in [0,U], masked phi for u in [0,U), umax.
__global__ __launch_bounds__(256) void k2_phi(const float* __restrict__ ws_in,
                                              const int* __restrict__ lens,
                                              float* __restrict__ out,
                                              float* __restrict__ ws) {
    const int b = blockIdx.y;
    const int u = blockIdx.x * 256 + threadIdx.x;
    __shared__ float a_s[K_SZ], b_s[K_SZ], n_s[K_SZ];
    if (threadIdx.x < 3 * K_SZ) {
        const int t = threadIdx.x;
        float v = ws_in[(t / K_SZ) * (B_SZ * K_SZ) + b * K_SZ + (t % K_SZ)];
        if (t < K_SZ)          a_s[t] = v;
        else if (t < 2 * K_SZ) b_s[t - K_SZ] = v;
        else                   n_s[t - 2 * K_SZ] = v;
    }
    __syncthreads();
    if (u > U_SZ) return;

    const float fu = (float)u;
    float s = 0.f;
    #pragma unroll
    for (int k = 0; k < K_SZ; ++k) {
        float d = n_s[k] - fu;
        s += a_s[k] * expf(-b_s[k] * d * d);
    }
    out[OUT_PT_OFF + (size_t)b * (U_SZ + 1) + u] = s;

    if (u < U_SZ) {
        float m = (u < lens[b]) ? s : 0.f;
        ws[WS_PHI_OFF + (size_t)b * U_SZ + u] = m;
        if (m != 0.f) {
            int* umax = (int*)(ws + WS_UMAX_OFF);
            atomicMax(&umax[b], u);
        }
    }
}

// Kernel 3: w[b,v] = sum_u phi[b,u] * c[b,u,v], only over rows with phi != 0.
__global__ __launch_bounds__(128) void k3_w(const float* __restrict__ c,
                                            const float* __restrict__ ws,
                                            float* __restrict__ out) {
    const int b = blockIdx.x;
    const int v = threadIdx.x;
    const int* umax = (const int*)(ws + WS_UMAX_OFF);
    const int ulim = umax[b] + 1;  // phi[b,u] == 0 exactly for all u > umax
    if (v >= V_SZ) return;
    const float* cb = c + (size_t)b * U_SZ * V_SZ;
    const float* pb = ws + WS_PHI_OFF + (size_t)b * U_SZ;
    float acc = 0.f;
    for (int u = 0; u < ulim; ++u) {
        acc += pb[u] * cb[(size_t)u * V_SZ + v];
    }
    out[OUT_W_OFF + b * V_SZ + v] = acc;
}

extern "C" void kernel_launch(void* const* d_in, const int* in_sizes, int n_in,
                              void* d_out, int out_size, void* d_ws, size_t ws_size,
                              hipStream_t stream) {
    const float* x     = (const float*)d_in[0];
    const float* c     = (const float*)d_in[1];
    const float* kappa = (const float*)d_in[2];
    const float* W     = (const float*)d_in[3];
    const float* bias  = (const float*)d_in[4];
    const int*   lens  = (const int*)d_in[5];
    float* out = (float*)d_out;
    float* ws  = (float*)d_ws;

    k1_lin<<<B_SZ, 256, 0, stream>>>(x, kappa, W, bias, ws, out);

    dim3 g2((U_SZ + 1 + 255) / 256, B_SZ);
    k2_phi<<<g2, 256, 0, stream>>>(ws, lens, out, ws);

    k3_w<<<B_SZ, 128, 0, stream>>>(c, ws, out);
}

// Round 2
// 23.646 us; speedup vs baseline: 1.4269x; 1.4269x over previous
//
#include <hip/hip_runtime.h>
#include <math.h>

#define B_SZ 256
#define U_SZ 4096
#define V_SZ 80
#define H_SZ 1024
#define K_SZ 10

// d_out layout (floats, concatenated in return order):
//   [0, B*V)                       w            (256*80   = 20480)
//   [B*V, B*V + B*K)               new_kappa    (256*10   = 2560)
//   [B*V + B*K, ... + B*(U+1))     phi_term     (256*4097 = 1048832)
#define OUT_W_OFF      0
#define OUT_NK_OFF     (B_SZ * V_SZ)
#define OUT_PT_OFF     (B_SZ * V_SZ + B_SZ * K_SZ)

// One block per batch. Phases:
//  1. stage x[b] (4 KB) in LDS
//  2. 30 dot products vs W rows (W cached in L2 across blocks)
//  3. alpha/beta/new_kappa + analytic cutoff ucut (terms beyond are < e^-60)
//  4. phi_termination: exp-compute u<=ucut, zero-fill the rest; masked phi -> LDS
//  5. w[b,v] = sum_{u<min(len,ucut+1)} phi[u] * c[b,u,v]
__global__ __launch_bounds__(256) void fused_softwindow(
        const float* __restrict__ x,
        const float* __restrict__ c,
        const float* __restrict__ kappa,
        const float* __restrict__ W,
        const float* __restrict__ bias,
        const int*   __restrict__ lens,
        float* __restrict__ out) {
    __shared__ float xs[H_SZ];
    __shared__ float lin_s[32];
    __shared__ float a_s[K_SZ], nb_s[K_SZ], nk_s[K_SZ], cut_s[K_SZ];
    __shared__ float phi_s[U_SZ];
    __shared__ float wpart[3][V_SZ];
    __shared__ int   ucut_s;

    const int b   = blockIdx.x;
    const int tid = threadIdx.x;

    // Phase 1: stage x[b]
    {
        const float4* xb4 = (const float4*)(x + (size_t)b * H_SZ);
        float4* xs4 = (float4*)xs;
        for (int i = tid; i < H_SZ / 4; i += 256) xs4[i] = xb4[i];
    }
    __syncthreads();

    // Phase 2: lin = x @ W.T (bias added later); 4 waves cover 30 rows
    {
        const int wave = tid >> 6;
        const int lane = tid & 63;
        for (int k = wave; k < 3 * K_SZ; k += 4) {
            const float* Wk = W + (size_t)k * H_SZ;
            float p = 0.f;
            #pragma unroll
            for (int h = lane; h < H_SZ; h += 64) p += xs[h] * Wk[h];
            #pragma unroll
            for (int off = 32; off > 0; off >>= 1) p += __shfl_down(p, off);
            if (lane == 0) lin_s[k] = p;
        }
    }
    __syncthreads();

    // Phase 3: per-k scalars + cutoff
    if (tid < K_SZ) {
        const int k = tid;
        float ah = lin_s[k]            + bias[k];
        float bh = lin_s[K_SZ + k]     + bias[K_SZ + k];
        float kh = lin_s[2 * K_SZ + k] + bias[2 * K_SZ + k];
        float alpha = expf(ah);
        float beta  = expf(bh);
        float nk    = kappa[(size_t)b * K_SZ + k] + expf(kh - 3.9f);
        a_s[k]  = alpha;
        nb_s[k] = -beta;
        nk_s[k] = nk;
        // term_k(u) = exp(ah - beta*(nk-u)^2) < e^-60 for u beyond this:
        cut_s[k] = nk + sqrtf((60.f + fmaxf(ah, 0.f)) / beta);
        out[OUT_NK_OFF + b * K_SZ + k] = nk;
    }
    __syncthreads();
    if (tid == 0) {
        float cmax = 0.f;
        #pragma unroll
        for (int k = 0; k < K_SZ; ++k) cmax = fmaxf(cmax, cut_s[k]);
        int uc = (int)cmax + 1;
        ucut_s = uc > U_SZ ? U_SZ : uc;
    }
    __syncthreads();

    const int ucut = ucut_s;
    const int len  = lens[b];
    float* pt = out + OUT_PT_OFF + (size_t)b * (U_SZ + 1);

    // Phase 4a: compute region u in [0, ucut]
    for (int u = tid; u <= ucut; u += 256) {
        const float fu = (float)u;
        float s = 0.f;
        #pragma unroll
        for (int k = 0; k < K_SZ; ++k) {
            float d = nk_s[k] - fu;
            s += a_s[k] * expf(nb_s[k] * d * d);
        }
        pt[u] = s;
        if (u < U_SZ) phi_s[u] = (u < len) ? s : 0.f;
    }
    // Phase 4b: zero-fill (ucut, U]
    for (int u = ucut + 1 + tid; u <= U_SZ; u += 256) pt[u] = 0.f;
    __syncthreads();

    // Phase 5: w[b,v] over u < ulim (phi is exactly 0 beyond)
    const int ulim = min(len, ucut + 1);
    if (tid < 240) {
        const int v = tid % V_SZ;
        const int r = tid / V_SZ;
        const float* cb = c + (size_t)b * U_SZ * V_SZ;
        float acc = 0.f;
        for (int u = r; u < ulim; u += 3) {
            acc += phi_s[u] * cb[(size_t)u * V_SZ + v];
        }
        wpart[r][v] = acc;
    }
    __syncthreads();
    if (tid < V_SZ) {
        out[OUT_W_OFF + b * V_SZ + tid] =
            wpart[0][tid] + wpart[1][tid] + wpart[2][tid];
    }
}

extern "C" void kernel_launch(void* const* d_in, const int* in_sizes, int n_in,
                              void* d_out, int out_size, void* d_ws, size_t ws_size,
                              hipStream_t stream) {
    const float* x     = (const float*)d_in[0];
    const float* c     = (const float*)d_in[1];
    const float* kappa = (const float*)d_in[2];
    const float* W     = (const float*)d_in[3];
    const float* bias  = (const float*)d_in[4];
    const int*   lens  = (const int*)d_in[5];
    float* out = (float*)d_out;

    fused_softwindow<<<B_SZ, 256, 0, stream>>>(x, c, kappa, W, bias, lens, out);
}

// Round 3
// 16.164 us; speedup vs baseline: 2.0875x; 1.4629x over previous
//
#include <hip/hip_runtime.h>
#include <math.h>

#define B_SZ 256
#define U_SZ 4096
#define V_SZ 80
#define H_SZ 1024
#define K_SZ 10
#define CPRE 64   // c rows prefetched into LDS per batch

// d_out layout (floats, concatenated in return order):
//   [0, B*V)                       w            (256*80   = 20480)
//   [B*V, B*V + B*K)               new_kappa    (256*10   = 2560)
//   [B*V + B*K, ... + B*(U+1))     phi_term     (256*4097 = 1048832)
#define OUT_W_OFF      0
#define OUT_NK_OFF     (B_SZ * V_SZ)
#define OUT_PT_OFF     (B_SZ * V_SZ + B_SZ * K_SZ)

// One block (1024 threads = 16 waves) per batch.
//  0. issue c-row prefetch (rows [0, min(len,CPRE)), contiguous 20 KB) + x stage
//  1. lin = x @ W.T: 16 waves cover 30 rows, float4 loads
//  2. alpha/beta/new_kappa + analytic cutoff (terms beyond are < e^-60)
//  3. phi_termination: exp only for u <= ucut, zero-fill rest; masked phi -> LDS
//  4. w[b,v] from LDS-cached c rows (global tail only if ulim > CPRE)
__global__ __launch_bounds__(1024) void fused_softwindow(
        const float* __restrict__ x,
        const float* __restrict__ c,
        const float* __restrict__ kappa,
        const float* __restrict__ W,
        const float* __restrict__ bias,
        const int*   __restrict__ lens,
        float* __restrict__ out) {
    __shared__ float xs[H_SZ];
    __shared__ float cs[CPRE * V_SZ];
    __shared__ float lin_s[32];
    __shared__ float a_s[K_SZ], nb_s[K_SZ], nk_s[K_SZ], cut_s[K_SZ];
    __shared__ float phi_s[U_SZ];
    __shared__ float wpart[12][V_SZ];
    __shared__ int   ucut_sh;

    const int b   = blockIdx.x;
    const int tid = threadIdx.x;
    const int len = lens[b];

    const float* cb = c + (size_t)b * U_SZ * V_SZ;

    // Phase 0a: c prefetch (independent of everything else; issued first so
    // its HBM latency overlaps phases 1-3)
    const int npre = min(len, CPRE);
    for (int i = tid; i < npre * V_SZ; i += 1024) cs[i] = cb[i];

    // Phase 0b: x stage
    {
        const float4* xb4 = (const float4*)(x + (size_t)b * H_SZ);
        float4* xs4 = (float4*)xs;
        for (int i = tid; i < H_SZ / 4; i += 1024) xs4[i] = xb4[i];
    }
    __syncthreads();

    // Phase 1: 30 dot products, 16 waves round-robin, float4 loads
    {
        const int wave = tid >> 6;
        const int lane = tid & 63;
        const float4* xs4 = (const float4*)xs;
        for (int k = wave; k < 3 * K_SZ; k += 16) {
            const float4* Wk4 = (const float4*)(W + (size_t)k * H_SZ);
            float p = 0.f;
            #pragma unroll
            for (int j = 0; j < 4; ++j) {
                float4 wv = Wk4[lane + 64 * j];
                float4 xv = xs4[lane + 64 * j];
                p += wv.x * xv.x + wv.y * xv.y + wv.z * xv.z + wv.w * xv.w;
            }
            #pragma unroll
            for (int off = 32; off > 0; off >>= 1) p += __shfl_down(p, off);
            if (lane == 0) lin_s[k] = p;
        }
    }
    __syncthreads();

    // Phase 2: per-k scalars + cutoff
    if (tid < K_SZ) {
        const int k = tid;
        float ah = lin_s[k]            + bias[k];
        float bh = lin_s[K_SZ + k]     + bias[K_SZ + k];
        float kh = lin_s[2 * K_SZ + k] + bias[2 * K_SZ + k];
        float alpha = expf(ah);
        float beta  = expf(bh);
        float nk    = kappa[(size_t)b * K_SZ + k] + expf(kh - 3.9f);
        a_s[k]  = alpha;
        nb_s[k] = -beta;
        nk_s[k] = nk;
        // term_k(u) = exp(ah - beta*(nk-u)^2) < e^-60 for u beyond this:
        cut_s[k] = nk + sqrtf((60.f + fmaxf(ah, 0.f)) / beta);
        out[OUT_NK_OFF + b * K_SZ + k] = nk;
    }
    __syncthreads();
    if (tid == 0) {
        float cmax = 0.f;
        #pragma unroll
        for (int k = 0; k < K_SZ; ++k) cmax = fmaxf(cmax, cut_s[k]);
        int uc = (int)cmax + 1;
        ucut_sh = uc > U_SZ ? U_SZ : uc;
    }
    __syncthreads();

    const int ucut = ucut_sh;
    float* pt = out + OUT_PT_OFF + (size_t)b * (U_SZ + 1);

    // Phase 3a: compute region u in [0, ucut] (typically one iteration)
    for (int u = tid; u <= ucut; u += 1024) {
        const float fu = (float)u;
        float s = 0.f;
        #pragma unroll
        for (int k = 0; k < K_SZ; ++k) {
            float d = nk_s[k] - fu;
            s += a_s[k] * expf(nb_s[k] * d * d);
        }
        pt[u] = s;
        if (u < U_SZ) phi_s[u] = (u < len) ? s : 0.f;
    }
    // Phase 3b: zero-fill (ucut, U]
    for (int u = ucut + 1 + tid; u <= U_SZ; u += 1024) pt[u] = 0.f;
    __syncthreads();

    // Phase 4: w[b,v] over u < ulim (phi exactly 0 beyond)
    const int ulim = min(len, ucut + 1);
    if (tid < 12 * V_SZ) {
        const int v = tid % V_SZ;
        const int r = tid / V_SZ;
        float acc = 0.f;
        const int lim1 = min(ulim, npre);
        for (int u = r; u < lim1; u += 12) {
            acc += phi_s[u] * cs[u * V_SZ + v];
        }
        if (ulim > CPRE) {  // rare tail: rows not prefetched
            int u0 = r + ((CPRE - r + 11) / 12) * 12;
            for (int u = u0; u < ulim; u += 12) {
                acc += phi_s[u] * cb[(size_t)u * V_SZ + v];
            }
        }
        wpart[r][v] = acc;
    }
    __syncthreads();
    if (tid < V_SZ) {
        float s = 0.f;
        #pragma unroll
        for (int r = 0; r < 12; ++r) s += wpart[r][tid];
        out[OUT_W_OFF + b * V_SZ + tid] = s;
    }
}

extern "C" void kernel_launch(void* const* d_in, const int* in_sizes, int n_in,
                              void* d_out, int out_size, void* d_ws, size_t ws_size,
                              hipStream_t stream) {
    const float* x     = (const float*)d_in[0];
    const float* c     = (const float*)d_in[1];
    const float* kappa = (const float*)d_in[2];
    const float* W     = (const float*)d_in[3];
    const float* bias  = (const float*)d_in[4];
    const int*   lens  = (const int*)d_in[5];
    float* out = (float*)d_out;

    fused_softwindow<<<B_SZ, 1024, 0, stream>>>(x, c, kappa, W, bias, lens, out);
}

// Round 5
// 11.788 us; speedup vs baseline: 2.8624x; 1.3712x over previous
//
#include <hip/hip_runtime.h>
#include <math.h>

#define B_SZ 256
#define U_SZ 4096
#define V_SZ 80
#define H_SZ 1024
#define K_SZ 10
#define CPRE 64   // c rows held in registers then LDS per batch
#define CPRE_F4 (CPRE * V_SZ / 4)   // 1280 float4

// d_out layout (floats, concatenated in return order):
//   [0, B*V)                       w            (256*80   = 20480)
//   [B*V, B*V + B*K)               new_kappa    (256*10   = 2560)
//   [B*V + B*K, ... + B*(U+1))     phi_term     (256*4097 = 1048832)
#define OUT_W_OFF      0
#define OUT_NK_OFF     (B_SZ * V_SZ)
#define OUT_PT_OFF     (B_SZ * V_SZ + B_SZ * K_SZ)

// One block (1024 threads = 16 waves) per batch. All HBM ops issued in the
// first pre-barrier region so their latency/BW overlaps the W-dot compute:
//   entry:  c rows (64x80 = 1280 float4) -> registers, kappa/bias prefetch,
//           zero phi_s (LDS)
//   pre-A:  lin = x @ W.T (x direct from global, L1-cached) ;
//           bulk zero-fill phi_term[CPRE..U] (the 4 MB output write)
//   A ----  (single drain point for all of the above)
//   creg -> LDS ; phase 2 scalars + analytic cutoff (terms beyond < e^-60)
//   B ----
//   phase 3: exp-compute pt[0..ucut] (+ phi_s), zero pt(ucut..CPRE)
//   D ----
//   phase 4: w from LDS c rows (+ rare global tail), reduce, store
__global__ __launch_bounds__(1024) void fused_softwindow(
        const float* __restrict__ x,
        const float* __restrict__ c,
        const float* __restrict__ kappa,
        const float* __restrict__ W,
        const float* __restrict__ bias,
        const int*   __restrict__ lens,
        float* __restrict__ out) {
    __shared__ float cs[CPRE * V_SZ];
    __shared__ float lin_s[32];
    __shared__ float a_s[K_SZ], nb_s[K_SZ], nk_s[K_SZ];
    __shared__ float phi_s[U_SZ];
    __shared__ float wpart[12][V_SZ];
    __shared__ int   ucut_sh;

    const int b    = blockIdx.x;
    const int tid  = threadIdx.x;
    const int wave = tid >> 6;
    const int lane = tid & 63;
    const int len  = lens[b];

    const float*  cb  = c + (size_t)b * U_SZ * V_SZ;
    const float4* cb4 = (const float4*)cb;

    // entry: c prefetch into registers — exactly CPRE_F4 = 1280 float4
    float4 creg0, creg1;
    creg0 = cb4[tid];                       // tid <  1024: always in range
    if (tid < CPRE_F4 - 1024) creg1 = cb4[tid + 1024];  // 256 threads

    // entry: kappa/bias prefetch (used by wave 0 in phase 2)
    float kap = 0.f, bs0 = 0.f, bs1 = 0.f, bs2 = 0.f;
    if (tid < K_SZ) {
        kap = kappa[b * K_SZ + tid];
        bs0 = bias[tid];
        bs1 = bias[K_SZ + tid];
        bs2 = bias[2 * K_SZ + tid];
    }

    // zero phi_s (same thread re-writes same indices in phase 3a)
    #pragma unroll
    for (int i = tid; i < U_SZ; i += 1024) phi_s[i] = 0.f;

    // phase 1: lin = x @ W.T, x and W direct from global
    {
        const float4* xb4 = (const float4*)(x + (size_t)b * H_SZ);
        float4 xv[4];
        #pragma unroll
        for (int j = 0; j < 4; ++j) xv[j] = xb4[lane + 64 * j];
        for (int k = wave; k < 3 * K_SZ; k += 16) {
            const float4* Wk4 = (const float4*)(W + (size_t)k * H_SZ);
            float p = 0.f;
            #pragma unroll
            for (int j = 0; j < 4; ++j) {
                float4 wv = Wk4[lane + 64 * j];
                p += wv.x * xv[j].x + wv.y * xv[j].y +
                     wv.z * xv[j].z + wv.w * xv[j].w;
            }
            #pragma unroll
            for (int off = 32; off > 0; off >>= 1) p += __shfl_down(p, off);
            if (lane == 0) lin_s[k] = p;
        }
    }

    // bulk zero-fill pt[CPRE..U] — overlaps phase 1, drains at A
    float* pt = out + OUT_PT_OFF + (size_t)b * (U_SZ + 1);
    for (int u = CPRE + tid; u <= U_SZ; u += 1024) pt[u] = 0.f;

    __syncthreads();  // A: lin_s ready; creg/x/W/zero-fill all drained here

    // creg -> LDS layout bounce (visible to phase 4 after barrier D)
    {
        float4* cs4 = (float4*)cs;
        cs4[tid] = creg0;
        if (tid < CPRE_F4 - 1024) cs4[tid + 1024] = creg1;
    }

    // phase 2: per-k scalars + in-wave cutoff reduce (wave 0 only)
    if (wave == 0) {
        float cut = 0.f;
        if (lane < K_SZ) {
            const int k = lane;
            float ah = lin_s[k]            + bs0;
            float bh = lin_s[K_SZ + k]     + bs1;
            float kh = lin_s[2 * K_SZ + k] + bs2;
            float alpha = expf(ah);
            float beta  = expf(bh);
            float nk    = kap + expf(kh - 3.9f);
            a_s[k]  = alpha;
            nb_s[k] = -beta;
            nk_s[k] = nk;
            // term_k(u) = exp(ah - beta*(nk-u)^2) < e^-60 beyond this u:
            cut = nk + sqrtf((60.f + fmaxf(ah, 0.f)) / beta);
            out[OUT_NK_OFF + b * K_SZ + k] = nk;
        }
        #pragma unroll
        for (int off = 8; off > 0; off >>= 1)
            cut = fmaxf(cut, __shfl_xor(cut, off));
        if (lane == 0) {
            int uc = (int)cut + 1;
            ucut_sh = uc > U_SZ ? U_SZ : uc;
        }
    }
    __syncthreads();  // B: a_s/nb_s/nk_s/ucut_sh + cs ready

    const int ucut = ucut_sh;

    // phase 3a: compute region u in [0, ucut] (typically one iteration)
    for (int u = tid; u <= ucut; u += 1024) {
        const float fu = (float)u;
        float s = 0.f;
        #pragma unroll
        for (int k = 0; k < K_SZ; ++k) {
            float d = nk_s[k] - fu;
            s += a_s[k] * expf(nb_s[k] * d * d);
        }
        pt[u] = s;
        if (u < len && u < U_SZ) phi_s[u] = s;
    }
    // phase 3b: zero the gap (ucut, CPRE) not covered by the bulk fill
    for (int u = ucut + 1 + tid; u < CPRE; u += 1024) pt[u] = 0.f;

    __syncthreads();  // D: phi_s ready

    // phase 4: w[b,v] (phi_s is exactly 0 beyond ulim)
    const int ulim = min(min(len, ucut + 1), U_SZ);
    if (tid < 12 * V_SZ) {
        const int v = tid % V_SZ;
        const int r = tid / V_SZ;
        float acc = 0.f;
        #pragma unroll
        for (int j = 0; j < 6; ++j) {
            const int u = r + 12 * j;
            if (u < CPRE) acc += phi_s[u] * cs[u * V_SZ + v];
        }
        if (ulim > CPRE) {  // rare tail: rows not prefetched
            int u0 = r + ((CPRE - r + 11) / 12) * 12;
            for (int u = u0; u < ulim; u += 12)
                acc += phi_s[u] * cb[(size_t)u * V_SZ + v];
        }
        wpart[r][v] = acc;
    }
    __syncthreads();  // E
    if (tid < V_SZ) {
        float s = 0.f;
        #pragma unroll
        for (int r = 0; r < 12; ++r) s += wpart[r][tid];
        out[OUT_W_OFF + b * V_SZ + tid] = s;
    }
}

extern "C" void kernel_launch(void* const* d_in, const int* in_sizes, int n_in,
                              void* d_out, int out_size, void* d_ws, size_t ws_size,
                              hipStream_t stream) {
    const float* x     = (const float*)d_in[0];
    const float* c     = (const float*)d_in[1];
    const float* kappa = (const float*)d_in[2];
    const float* W     = (const float*)d_in[3];
    const float* bias  = (const float*)d_in[4];
    const int*   lens  = (const int*)d_in[5];
    float* out = (float*)d_out;

    fused_softwindow<<<B_SZ, 1024, 0, stream>>>(x, c, kappa, W, bias, lens, out);
}